// Round 5
// baseline (223.162 us; speedup 1.0000x reference)
//
#include <hip/hip_runtime.h>

// GCN edge predictor, collapsed to scalar-per-node linear algebra:
//   u_i = x_i . w1c ;  v = A u + c1 ;  t = A v + c2 ;  out[g] = sum_g t + c0
//   A = D^-1/2 (Adj + I) D^-1/2
// R9: kill the scatter scratch spill for real + coarser buckets.
//   - 8 edges/thread (STAGE_CAP 4096), staging state as 26 NAMED SCALARS
//     (literal indices only -> cannot demote to scratch). R8 still spilled
//     (VGPR=52 < 52 array words; WRITE_SIZE 25.9MB vs 13.6 expected).
//   - RSHIFT 9: 512-node buckets, nb=196, NB_MAX=256 -> uchar bof, 24KB LDS,
//     256-entry scan, ~21-edge flush segments, conv blocks 4x fatter.
//   - conv/degree kernels: 1024 threads (3 waves/SIMD gather TLP).
//   Pipeline: collapse, scatter+u, degree_dinv, conv_mid, conv_final (5).

#define RSHIFT 9
#define RNODES 512           // nodes per bucket
#define NB_MAX 256           // max buckets (n <= 131072)
#define STHREADS 512         // scatter threads
#define CTHREADS 1024        // conv/degree threads
#define STAGE_CAP 4096       // edges per tile (8 per thread)
#define BCAP 20480           // per-bucket slab capacity (mean ~16.3K, +32 sigma)

__global__ void collapse_weights_k(
    const float* __restrict__ W1, const float* __restrict__ b1,
    const float* __restrict__ W2, const float* __restrict__ b2,
    const float* __restrict__ Wf1, const float* __restrict__ bf1,
    const float* __restrict__ Wf2, const float* __restrict__ bf2,
    const float* __restrict__ Wf3, const float* __restrict__ bf3,
    const float* __restrict__ Wo, const float* __restrict__ bo,
    float* __restrict__ w1c, float* __restrict__ sc,
    int* __restrict__ cursor, float* __restrict__ out, int G)
{
    __shared__ float wo[10], w3[20], w2[30], w1[50], w2c[60];
    __shared__ float c0s;
    const int t = threadIdx.x;  // 64 threads
    for (int b = t; b < NB_MAX; b += 64) cursor[b] = 0;
    if (t < 10) wo[t] = Wo[t];
    __syncthreads();
    if (t < 20) { float s = 0.f; for (int j = 0; j < 10; ++j) s += Wf3[t*10+j]*wo[j]; w3[t] = s; }
    __syncthreads();
    if (t < 30) { float s = 0.f; for (int j = 0; j < 20; ++j) s += Wf2[t*20+j]*w3[j]; w2[t] = s; }
    __syncthreads();
    if (t < 50) { float s = 0.f; for (int j = 0; j < 30; ++j) s += Wf1[t*30+j]*w2[j]; w1[t] = s; }
    __syncthreads();
    if (t < 60) { float s = 0.f; for (int j = 0; j < 50; ++j) s += W2[t*50+j]*w1[j]; w2c[t] = s; }
    __syncthreads();
    { float s = 0.f; for (int j = 0; j < 60; ++j) s += W1[t*60+j]*w2c[j]; w1c[t] = s; }
    if (t == 0) {
        float c1 = 0.f; for (int j = 0; j < 60; ++j) c1 += b1[j]*w2c[j];
        float c2 = 0.f; for (int j = 0; j < 50; ++j) c2 += b2[j]*w1[j];
        float c0 = bo[0];
        for (int j = 0; j < 30; ++j) c0 += bf1[j]*w2[j];
        for (int j = 0; j < 20; ++j) c0 += bf2[j]*w3[j];
        for (int j = 0; j < 10; ++j) c0 += bf3[j]*wo[j];
        sc[0] = c1; sc[1] = c2; sc[2] = c0;
        c0s = c0;
    }
    __syncthreads();
    for (int g = t; g < G; g += 64) out[g] = c0s;
}

// Fused: (A) u for this block's node slice; (B) scatter tile bx into slabs.
// All per-edge staging state in NAMED SCALARS -> guaranteed register-resident.
__global__ __launch_bounds__(STHREADS, 4)
void scatter_u_k(const float* __restrict__ x, const float* __restrict__ w1c,
                 float* __restrict__ u,
                 const int* __restrict__ src, const int* __restrict__ dst,
                 int E, int n, int npb, int nb,
                 int* __restrict__ cursor, unsigned int* __restrict__ binned) {
    __shared__ int hist[NB_MAX];
    __shared__ int tbase[NB_MAX];
    __shared__ int adj[NB_MAX];
    __shared__ int sums[NB_MAX];
    __shared__ unsigned int staged[STAGE_CAP];
    __shared__ unsigned char bof[STAGE_CAP];
    const int tid = threadIdx.x;
    const int bx = blockIdx.x;

    // ---- (A) u for nodes [bx*npb, bx*npb+npb) ----
    {
        const int grp = tid >> 4, sub = tid & 15;
        float4 wv = *reinterpret_cast<const float4*>(w1c + sub * 4);
        int base = bx * npb;
        for (int p = 0; p * 32 < npb; ++p) {
            int nl = p * 32 + grp;
            int g = base + nl;
            bool ok = (nl < npb) && (g < n);
            float val = 0.f;
            if (ok) {
                float4 xv = *reinterpret_cast<const float4*>(
                    x + (size_t)g * 64 + sub * 4);
                val = xv.x*wv.x + xv.y*wv.y + xv.z*wv.z + xv.w*wv.w;
            }
            val += __shfl_down(val, 8, 16);
            val += __shfl_down(val, 4, 16);
            val += __shfl_down(val, 2, 16);
            val += __shfl_down(val, 1, 16);
            if (ok && sub == 0) u[g] = val;
        }
    }

    // ---- (B) scatter tile bx ----
    if (tid < NB_MAX) hist[tid] = 0;
    __syncthreads();
    int e0 = bx * STAGE_CAP;
    int e1 = e0 + STAGE_CAP; if (e1 > E) e1 = E;

    unsigned pk0=0,pk1=0,pk2=0,pk3=0,pk4=0,pk5=0,pk6=0,pk7=0;
    int bk0=0,bk1=0,bk2=0,bk3=0,bk4=0,bk5=0,bk6=0,bk7=0;
    int rk0=0,rk1=0,rk2=0,rk3=0,rk4=0,rk5=0,rk6=0,rk7=0;
    int iA = e0 + tid * 4;
    int iB = iA + STHREADS * 4;
    int cA = e1 - iA; if (cA > 4) cA = 4; if (cA < 0) cA = 0;
    int cB = e1 - iB; if (cB > 4) cB = 4; if (cB < 0) cB = 0;

    if (cA == 4) {
        int4 s4 = *reinterpret_cast<const int4*>(src + iA);
        int4 d4 = *reinterpret_cast<const int4*>(dst + iA);
        pk0 = (unsigned)s4.x | ((unsigned)(d4.x & (RNODES-1)) << 17);
        pk1 = (unsigned)s4.y | ((unsigned)(d4.y & (RNODES-1)) << 17);
        pk2 = (unsigned)s4.z | ((unsigned)(d4.z & (RNODES-1)) << 17);
        pk3 = (unsigned)s4.w | ((unsigned)(d4.w & (RNODES-1)) << 17);
        bk0 = d4.x >> RSHIFT; bk1 = d4.y >> RSHIFT;
        bk2 = d4.z >> RSHIFT; bk3 = d4.w >> RSHIFT;
        rk0 = atomicAdd(&hist[bk0], 1);
        rk1 = atomicAdd(&hist[bk1], 1);
        rk2 = atomicAdd(&hist[bk2], 1);
        rk3 = atomicAdd(&hist[bk3], 1);
    } else {
        if (cA > 0) { int s=src[iA],   d=dst[iA];   pk0=(unsigned)s|((unsigned)(d&(RNODES-1))<<17); bk0=d>>RSHIFT; rk0=atomicAdd(&hist[bk0],1); }
        if (cA > 1) { int s=src[iA+1], d=dst[iA+1]; pk1=(unsigned)s|((unsigned)(d&(RNODES-1))<<17); bk1=d>>RSHIFT; rk1=atomicAdd(&hist[bk1],1); }
        if (cA > 2) { int s=src[iA+2], d=dst[iA+2]; pk2=(unsigned)s|((unsigned)(d&(RNODES-1))<<17); bk2=d>>RSHIFT; rk2=atomicAdd(&hist[bk2],1); }
    }
    if (cB == 4) {
        int4 s4 = *reinterpret_cast<const int4*>(src + iB);
        int4 d4 = *reinterpret_cast<const int4*>(dst + iB);
        pk4 = (unsigned)s4.x | ((unsigned)(d4.x & (RNODES-1)) << 17);
        pk5 = (unsigned)s4.y | ((unsigned)(d4.y & (RNODES-1)) << 17);
        pk6 = (unsigned)s4.z | ((unsigned)(d4.z & (RNODES-1)) << 17);
        pk7 = (unsigned)s4.w | ((unsigned)(d4.w & (RNODES-1)) << 17);
        bk4 = d4.x >> RSHIFT; bk5 = d4.y >> RSHIFT;
        bk6 = d4.z >> RSHIFT; bk7 = d4.w >> RSHIFT;
        rk4 = atomicAdd(&hist[bk4], 1);
        rk5 = atomicAdd(&hist[bk5], 1);
        rk6 = atomicAdd(&hist[bk6], 1);
        rk7 = atomicAdd(&hist[bk7], 1);
    } else {
        if (cB > 0) { int s=src[iB],   d=dst[iB];   pk4=(unsigned)s|((unsigned)(d&(RNODES-1))<<17); bk4=d>>RSHIFT; rk4=atomicAdd(&hist[bk4],1); }
        if (cB > 1) { int s=src[iB+1], d=dst[iB+1]; pk5=(unsigned)s|((unsigned)(d&(RNODES-1))<<17); bk5=d>>RSHIFT; rk5=atomicAdd(&hist[bk5],1); }
        if (cB > 2) { int s=src[iB+2], d=dst[iB+2]; pk6=(unsigned)s|((unsigned)(d&(RNODES-1))<<17); bk6=d>>RSHIFT; rk6=atomicAdd(&hist[bk6],1); }
    }
    __syncthreads();

    // exclusive scan over NB_MAX=256 bucket counts (Hillis-Steele, 8 steps)
    int h = (tid < NB_MAX) ? hist[tid] : 0;
    if (tid < NB_MAX) sums[tid] = h;
    __syncthreads();
    for (int off = 1; off < NB_MAX; off <<= 1) {
        int a = (tid >= off && tid < NB_MAX) ? sums[tid - off] : 0;
        __syncthreads();
        if (tid < NB_MAX) sums[tid] += a;
        __syncthreads();
    }
    if (tid < NB_MAX) {
        int excl = sums[tid] - h;
        tbase[tid] = excl;
        if (tid < nb && h > 0) {
            int r = atomicAdd(&cursor[tid], h);
            adj[tid] = tid * BCAP + r - excl;
        }
    }
    __syncthreads();

    // write bucket-sorted into LDS (literal-index scalar stores)
    if (cA > 0) { int s2 = tbase[bk0] + rk0; staged[s2] = pk0; bof[s2] = (unsigned char)bk0; }
    if (cA > 1) { int s2 = tbase[bk1] + rk1; staged[s2] = pk1; bof[s2] = (unsigned char)bk1; }
    if (cA > 2) { int s2 = tbase[bk2] + rk2; staged[s2] = pk2; bof[s2] = (unsigned char)bk2; }
    if (cA > 3) { int s2 = tbase[bk3] + rk3; staged[s2] = pk3; bof[s2] = (unsigned char)bk3; }
    if (cB > 0) { int s2 = tbase[bk4] + rk4; staged[s2] = pk4; bof[s2] = (unsigned char)bk4; }
    if (cB > 1) { int s2 = tbase[bk5] + rk5; staged[s2] = pk5; bof[s2] = (unsigned char)bk5; }
    if (cB > 2) { int s2 = tbase[bk6] + rk6; staged[s2] = pk6; bof[s2] = (unsigned char)bk6; }
    if (cB > 3) { int s2 = tbase[bk7] + rk7; staged[s2] = pk7; bof[s2] = (unsigned char)bk7; }
    __syncthreads();

    // dense flush (consecutive s -> mostly consecutive global addresses)
    int tcount = e1 - e0;
    for (int s2 = tid; s2 < tcount; s2 += STHREADS) {
        int b = bof[s2];
        binned[adj[b] + s2] = staged[s2];
    }
}

// per-bucket in-degree histogram in LDS -> dinv = rsqrt(deg+1); w = dinv * u
__global__ void degree_dinv_k(const unsigned int* __restrict__ binned,
                              const int* __restrict__ cursor,
                              const float* __restrict__ u,
                              float* __restrict__ dinv, float* __restrict__ w, int n) {
    __shared__ int cnt[RNODES];
    int tid = threadIdx.x, b = blockIdx.x;
    if (tid < RNODES) cnt[tid] = 0;
    __syncthreads();
    size_t s0 = (size_t)b * BCAP;
    int c = cursor[b];
    if (c > BCAP) c = BCAP;
    int nvec = c >> 2;
    for (int k = tid; k < nvec; k += blockDim.x) {
        uint4 p = *reinterpret_cast<const uint4*>(binned + s0 + 4 * k);
        atomicAdd(&cnt[p.x >> 17], 1);
        atomicAdd(&cnt[p.y >> 17], 1);
        atomicAdd(&cnt[p.z >> 17], 1);
        atomicAdd(&cnt[p.w >> 17], 1);
    }
    int i = 4 * nvec + tid;
    if (i < c) atomicAdd(&cnt[binned[s0 + i] >> 17], 1);
    __syncthreads();
    int g = (b << RSHIFT) + tid;
    if (tid < RNODES && g < n) {
        float d = rsqrtf((float)(cnt[tid] + 1));
        dinv[g] = d;
        w[g] = d * u[g];
    }
}

// v = c1 + dinv*(sum of w[src]) + dinv^2*u ; wb = dinv*v
__global__ void conv_mid_k(const unsigned int* __restrict__ binned,
                           const int* __restrict__ cursor,
                           const float* __restrict__ w, const float* __restrict__ dinv,
                           const float* __restrict__ u, const float* __restrict__ sc,
                           float* __restrict__ v, float* __restrict__ wb, int n) {
    __shared__ float acc[RNODES];
    int tid = threadIdx.x, b = blockIdx.x;
    if (tid < RNODES) acc[tid] = 0.f;
    __syncthreads();
    size_t s0 = (size_t)b * BCAP;
    int cnt = cursor[b];
    if (cnt > BCAP) cnt = BCAP;
    int nvec = cnt >> 2;
    for (int k = tid; k < nvec; k += blockDim.x) {
        uint4 p = *reinterpret_cast<const uint4*>(binned + s0 + 4 * k);
        float wx = w[p.x & 0x1FFFF];
        float wy = w[p.y & 0x1FFFF];
        float wz = w[p.z & 0x1FFFF];
        float ww = w[p.w & 0x1FFFF];
        atomicAdd(&acc[p.x >> 17], wx);
        atomicAdd(&acc[p.y >> 17], wy);
        atomicAdd(&acc[p.z >> 17], wz);
        atomicAdd(&acc[p.w >> 17], ww);
    }
    int i = 4 * nvec + tid;
    if (i < cnt) { unsigned p = binned[s0 + i]; atomicAdd(&acc[p >> 17], w[p & 0x1FFFF]); }
    __syncthreads();
    int g = (b << RSHIFT) + tid;
    if (tid < RNODES && g < n) {
        float di = dinv[g];
        float val = sc[0] + di * acc[tid] + di * di * u[g];
        v[g] = val;
        wb[g] = di * val;
    }
}

// t = c2 + dinv*sum + dinv^2*v, then segmented pool by sorted batch id
__global__ void conv_final_k(const unsigned int* __restrict__ binned,
                             const int* __restrict__ cursor,
                             const float* __restrict__ wb, const float* __restrict__ dinv,
                             const float* __restrict__ v, const float* __restrict__ sc,
                             const int* __restrict__ batch, float* __restrict__ out, int n) {
    __shared__ float acc[RNODES];
    __shared__ float tbuf[RNODES];
    __shared__ int gbuf[RNODES];
    int tid = threadIdx.x, b = blockIdx.x;
    if (tid < RNODES) acc[tid] = 0.f;
    __syncthreads();
    size_t s0 = (size_t)b * BCAP;
    int cnt = cursor[b];
    if (cnt > BCAP) cnt = BCAP;
    int nvec = cnt >> 2;
    for (int k = tid; k < nvec; k += blockDim.x) {
        uint4 p = *reinterpret_cast<const uint4*>(binned + s0 + 4 * k);
        float wx = wb[p.x & 0x1FFFF];
        float wy = wb[p.y & 0x1FFFF];
        float wz = wb[p.z & 0x1FFFF];
        float ww = wb[p.w & 0x1FFFF];
        atomicAdd(&acc[p.x >> 17], wx);
        atomicAdd(&acc[p.y >> 17], wy);
        atomicAdd(&acc[p.z >> 17], wz);
        atomicAdd(&acc[p.w >> 17], ww);
    }
    int i = 4 * nvec + tid;
    if (i < cnt) { unsigned p = binned[s0 + i]; atomicAdd(&acc[p >> 17], wb[p & 0x1FFFF]); }
    __syncthreads();
    int g = (b << RSHIFT) + tid;
    float tval = 0.f; int gid = -1;
    if (tid < RNODES && g < n) {
        float di = dinv[g];
        tval = sc[1] + di * acc[tid] + di * di * v[g];
        gid = batch[g];
    }
    if (tid < RNODES) { tbuf[tid] = tval; gbuf[tid] = gid; }
    __syncthreads();
    if (tid < RNODES && g < n) {
        bool head = (tid == 0) || (gbuf[tid - 1] != gid);
        if (head) {
            float s = 0.f;
            int i2 = tid;
            while (i2 < RNODES && gbuf[i2] == gid) { s += tbuf[i2]; ++i2; }
            atomicAdd(&out[gid], s);
        }
    }
}

extern "C" void kernel_launch(void* const* d_in, const int* in_sizes, int n_in,
                              void* d_out, int out_size, void* d_ws, size_t ws_size,
                              hipStream_t stream)
{
    const float* x    = (const float*)d_in[0];
    const int*   ei   = (const int*)d_in[1];
    const int*   batch= (const int*)d_in[2];
    const float* W1   = (const float*)d_in[3];
    const float* b1   = (const float*)d_in[4];
    const float* W2   = (const float*)d_in[5];
    const float* b2   = (const float*)d_in[6];
    const float* Wf1  = (const float*)d_in[7];
    const float* bf1  = (const float*)d_in[8];
    const float* Wf2  = (const float*)d_in[9];
    const float* bf2  = (const float*)d_in[10];
    const float* Wf3  = (const float*)d_in[11];
    const float* bf3  = (const float*)d_in[12];
    const float* Wo   = (const float*)d_in[13];
    const float* bo   = (const float*)d_in[14];
    float* out = (float*)d_out;

    const int n = in_sizes[0] / 64;
    const int E = in_sizes[1] / 2;
    const int G = out_size;
    const int* src = ei;
    const int* dst = ei + E;
    const int nb = (n + RNODES - 1) >> RSHIFT;

    // workspace layout (element offsets, all blocks 16B-aligned)
    float* ws_f = (float*)d_ws;
    int*   ws_i = (int*)d_ws;
    float* w1c    = ws_f;                    // 64
    float* sc     = ws_f + 64;               // 3 (+pad to 128)
    int*   cursor = ws_i + 128;              // NB_MAX (256)
    size_t off_u  = 128 + (size_t)NB_MAX;
    float* u      = ws_f + off_u;            // n
    float* dinv   = u + n;                   // n
    float* w      = dinv + n;                // n
    float* v      = w + n;                   // n
    float* wb     = v + n;                   // n
    size_t off_b  = off_u + 5*(size_t)n;
    off_b = (off_b + 3) & ~(size_t)3;
    unsigned int* binned = (unsigned int*)(ws_f + off_b);   // nb * BCAP

    const int NT = (E + STAGE_CAP - 1) / STAGE_CAP;   // scatter tiles
    const int npb = (n + NT - 1) / NT;                // nodes per tile for u

    hipLaunchKernelGGL(collapse_weights_k, dim3(1), dim3(64), 0, stream,
                       W1, b1, W2, b2, Wf1, bf1, Wf2, bf2, Wf3, bf3, Wo, bo,
                       w1c, sc, cursor, out, G);
    hipLaunchKernelGGL(scatter_u_k, dim3(NT), dim3(STHREADS), 0, stream,
                       x, w1c, u, src, dst, E, n, npb, nb, cursor, binned);
    hipLaunchKernelGGL(degree_dinv_k, dim3(nb), dim3(CTHREADS), 0, stream,
                       binned, cursor, u, dinv, w, n);
    hipLaunchKernelGGL(conv_mid_k, dim3(nb), dim3(CTHREADS), 0, stream,
                       binned, cursor, w, dinv, u, sc, v, wb, n);
    hipLaunchKernelGGL(conv_final_k, dim3(nb), dim3(CTHREADS), 0, stream,
                       binned, cursor, wb, dinv, v, sc, batch, out, n);
}

// Round 6
// 206.956 us; speedup vs baseline: 1.0783x; 1.0783x over previous
//
#include <hip/hip_runtime.h>

// GCN edge predictor, collapsed to scalar-per-node linear algebra:
//   u_i = x_i . w1c ;  v = A u + c1 ;  t = A v + c2 ;  out[g] = sum_g t + c0
//   A = D^-1/2 (Adj + I) D^-1/2
// R10: revert to RSHIFT=7 conv geometry (R9's 196-block grids were
//   latency-bound at 14% occupancy: gather passes scale with resident
//   waves, not BW). Keep R9's named-scalar spill-free scatter, now at
//   16 edges/thread (4 quad groups). Conv/degree: 782 blocks x 512 thr,
//   launch_bounds(512,8) -> 4 blocks/CU, all gathers issued as named
//   scalars before any LDS atomic (max MLP, no runtime-indexed arrays).
//   Pipeline: collapse, scatter+u, degree_dinv, conv_mid, conv_final (5).

#define RSHIFT 7
#define RNODES 128           // nodes per bucket
#define NB_MAX 1024          // max buckets (n <= 131072; src fits 17 bits)
#define STHREADS 512         // scatter threads
#define CTHREADS 512         // conv/degree threads
#define STAGE_CAP 8192       // edges per tile (16 per thread)
#define BCAP 6144            // per-bucket slab capacity (mean ~4092, +32 sigma)

__global__ void collapse_weights_k(
    const float* __restrict__ W1, const float* __restrict__ b1,
    const float* __restrict__ W2, const float* __restrict__ b2,
    const float* __restrict__ Wf1, const float* __restrict__ bf1,
    const float* __restrict__ Wf2, const float* __restrict__ bf2,
    const float* __restrict__ Wf3, const float* __restrict__ bf3,
    const float* __restrict__ Wo, const float* __restrict__ bo,
    float* __restrict__ w1c, float* __restrict__ sc,
    int* __restrict__ cursor, float* __restrict__ out, int G)
{
    __shared__ float wo[10], w3[20], w2[30], w1[50], w2c[60];
    __shared__ float c0s;
    const int t = threadIdx.x;  // 64 threads
    for (int b = t; b < NB_MAX; b += 64) cursor[b] = 0;
    if (t < 10) wo[t] = Wo[t];
    __syncthreads();
    if (t < 20) { float s = 0.f; for (int j = 0; j < 10; ++j) s += Wf3[t*10+j]*wo[j]; w3[t] = s; }
    __syncthreads();
    if (t < 30) { float s = 0.f; for (int j = 0; j < 20; ++j) s += Wf2[t*20+j]*w3[j]; w2[t] = s; }
    __syncthreads();
    if (t < 50) { float s = 0.f; for (int j = 0; j < 30; ++j) s += Wf1[t*30+j]*w2[j]; w1[t] = s; }
    __syncthreads();
    if (t < 60) { float s = 0.f; for (int j = 0; j < 50; ++j) s += W2[t*50+j]*w1[j]; w2c[t] = s; }
    __syncthreads();
    { float s = 0.f; for (int j = 0; j < 60; ++j) s += W1[t*60+j]*w2c[j]; w1c[t] = s; }
    if (t == 0) {
        float c1 = 0.f; for (int j = 0; j < 60; ++j) c1 += b1[j]*w2c[j];
        float c2 = 0.f; for (int j = 0; j < 50; ++j) c2 += b2[j]*w1[j];
        float c0 = bo[0];
        for (int j = 0; j < 30; ++j) c0 += bf1[j]*w2[j];
        for (int j = 0; j < 20; ++j) c0 += bf2[j]*w3[j];
        for (int j = 0; j < 10; ++j) c0 += bf3[j]*wo[j];
        sc[0] = c1; sc[1] = c2; sc[2] = c0;
        c0s = c0;
    }
    __syncthreads();
    for (int g = t; g < G; g += 64) out[g] = c0s;
}

// one quad-group of the scatter staging, all state in caller-named scalars
#define LOAD_QUAD(ii, cc, P0, P1, P2, P3, B0, B1, B2, B3, R0, R1, R2, R3)     \
    if (cc == 4) {                                                            \
        int4 s4 = *reinterpret_cast<const int4*>(src + ii);                   \
        int4 d4 = *reinterpret_cast<const int4*>(dst + ii);                   \
        P0 = (unsigned)s4.x | ((unsigned)(d4.x & (RNODES-1)) << 17);          \
        P1 = (unsigned)s4.y | ((unsigned)(d4.y & (RNODES-1)) << 17);          \
        P2 = (unsigned)s4.z | ((unsigned)(d4.z & (RNODES-1)) << 17);          \
        P3 = (unsigned)s4.w | ((unsigned)(d4.w & (RNODES-1)) << 17);          \
        B0 = d4.x >> RSHIFT; B1 = d4.y >> RSHIFT;                             \
        B2 = d4.z >> RSHIFT; B3 = d4.w >> RSHIFT;                             \
        R0 = atomicAdd(&hist[B0], 1);                                         \
        R1 = atomicAdd(&hist[B1], 1);                                         \
        R2 = atomicAdd(&hist[B2], 1);                                         \
        R3 = atomicAdd(&hist[B3], 1);                                         \
    } else {                                                                  \
        if (cc > 0) { int s=src[ii],   d=dst[ii];   P0=(unsigned)s|((unsigned)(d&(RNODES-1))<<17); B0=d>>RSHIFT; R0=atomicAdd(&hist[B0],1); } \
        if (cc > 1) { int s=src[ii+1], d=dst[ii+1]; P1=(unsigned)s|((unsigned)(d&(RNODES-1))<<17); B1=d>>RSHIFT; R1=atomicAdd(&hist[B1],1); } \
        if (cc > 2) { int s=src[ii+2], d=dst[ii+2]; P2=(unsigned)s|((unsigned)(d&(RNODES-1))<<17); B2=d>>RSHIFT; R2=atomicAdd(&hist[B2],1); } \
    }

#define STORE_QUAD(cc, P0, P1, P2, P3, B0, B1, B2, B3, R0, R1, R2, R3)        \
    if (cc > 0) { int s2 = tbase[B0] + R0; staged[s2] = P0; bof[s2] = (unsigned short)B0; } \
    if (cc > 1) { int s2 = tbase[B1] + R1; staged[s2] = P1; bof[s2] = (unsigned short)B1; } \
    if (cc > 2) { int s2 = tbase[B2] + R2; staged[s2] = P2; bof[s2] = (unsigned short)B2; } \
    if (cc > 3) { int s2 = tbase[B3] + R3; staged[s2] = P3; bof[s2] = (unsigned short)B3; }

// Fused: (A) u for this block's node slice; (B) scatter tile bx into slabs.
__global__ __launch_bounds__(STHREADS, 4)
void scatter_u_k(const float* __restrict__ x, const float* __restrict__ w1c,
                 float* __restrict__ u,
                 const int* __restrict__ src, const int* __restrict__ dst,
                 int E, int n, int npb, int nb,
                 int* __restrict__ cursor, unsigned int* __restrict__ binned) {
    __shared__ int hist[NB_MAX];
    __shared__ int tbase[NB_MAX];
    __shared__ int adj[NB_MAX];
    __shared__ int sums[STHREADS];
    __shared__ unsigned int staged[STAGE_CAP];
    __shared__ unsigned short bof[STAGE_CAP];
    const int tid = threadIdx.x;
    const int bx = blockIdx.x;

    // ---- (A) u for nodes [bx*npb, bx*npb+npb) ----
    {
        const int grp = tid >> 4, sub = tid & 15;
        float4 wv = *reinterpret_cast<const float4*>(w1c + sub * 4);
        int base = bx * npb;
        for (int p = 0; p * 32 < npb; ++p) {
            int nl = p * 32 + grp;
            int g = base + nl;
            bool ok = (nl < npb) && (g < n);
            float val = 0.f;
            if (ok) {
                float4 xv = *reinterpret_cast<const float4*>(
                    x + (size_t)g * 64 + sub * 4);
                val = xv.x*wv.x + xv.y*wv.y + xv.z*wv.z + xv.w*wv.w;
            }
            val += __shfl_down(val, 8, 16);
            val += __shfl_down(val, 4, 16);
            val += __shfl_down(val, 2, 16);
            val += __shfl_down(val, 1, 16);
            if (ok && sub == 0) u[g] = val;
        }
    }

    // ---- (B) scatter tile bx: 16 edges/thread in 4 named quad groups ----
    hist[tid] = 0; hist[tid + STHREADS] = 0;
    __syncthreads();
    int e0 = bx * STAGE_CAP;
    int e1 = e0 + STAGE_CAP; if (e1 > E) e1 = E;

    unsigned pa0=0,pa1=0,pa2=0,pa3=0, pb0=0,pb1=0,pb2=0,pb3=0;
    unsigned pc0=0,pc1=0,pc2=0,pc3=0, pd0=0,pd1=0,pd2=0,pd3=0;
    int ba0=0,ba1=0,ba2=0,ba3=0, bb0=0,bb1=0,bb2=0,bb3=0;
    int bc0=0,bc1=0,bc2=0,bc3=0, bd0=0,bd1=0,bd2=0,bd3=0;
    int ra0=0,ra1=0,ra2=0,ra3=0, rb0=0,rb1=0,rb2=0,rb3=0;
    int rc0=0,rc1=0,rc2=0,rc3=0, rd0=0,rd1=0,rd2=0,rd3=0;

    int iA = e0 + tid * 4;
    int iB = iA + STHREADS * 4;
    int iC = iB + STHREADS * 4;
    int iD = iC + STHREADS * 4;
    int cA = e1 - iA; if (cA > 4) cA = 4; if (cA < 0) cA = 0;
    int cB = e1 - iB; if (cB > 4) cB = 4; if (cB < 0) cB = 0;
    int cC = e1 - iC; if (cC > 4) cC = 4; if (cC < 0) cC = 0;
    int cD = e1 - iD; if (cD > 4) cD = 4; if (cD < 0) cD = 0;

    LOAD_QUAD(iA, cA, pa0,pa1,pa2,pa3, ba0,ba1,ba2,ba3, ra0,ra1,ra2,ra3)
    LOAD_QUAD(iB, cB, pb0,pb1,pb2,pb3, bb0,bb1,bb2,bb3, rb0,rb1,rb2,rb3)
    LOAD_QUAD(iC, cC, pc0,pc1,pc2,pc3, bc0,bc1,bc2,bc3, rc0,rc1,rc2,rc3)
    LOAD_QUAD(iD, cD, pd0,pd1,pd2,pd3, bd0,bd1,bd2,bd3, rd0,rd1,rd2,rd3)
    __syncthreads();

    // block-exclusive scan of hist[0..1023] (2 slots per thread)
    int h0 = hist[2*tid], h1 = hist[2*tid+1];
    int pair = h0 + h1;
    sums[tid] = pair;
    __syncthreads();
    for (int off = 1; off < STHREADS; off <<= 1) {
        int a = (tid >= off) ? sums[tid - off] : 0;
        __syncthreads();
        sums[tid] += a;
        __syncthreads();
    }
    int excl = sums[tid] - pair;
    tbase[2*tid] = excl;
    tbase[2*tid+1] = excl + h0;
    // reserve this tile's segment in each bucket's slab
    {
        int b0 = 2*tid, b1 = 2*tid + 1;
        if (b0 < nb && h0 > 0) {
            int r = atomicAdd(&cursor[b0], h0);
            adj[b0] = b0 * BCAP + r - excl;
        }
        if (b1 < nb && h1 > 0) {
            int r = atomicAdd(&cursor[b1], h1);
            adj[b1] = b1 * BCAP + r - (excl + h0);
        }
    }
    __syncthreads();

    STORE_QUAD(cA, pa0,pa1,pa2,pa3, ba0,ba1,ba2,ba3, ra0,ra1,ra2,ra3)
    STORE_QUAD(cB, pb0,pb1,pb2,pb3, bb0,bb1,bb2,bb3, rb0,rb1,rb2,rb3)
    STORE_QUAD(cC, pc0,pc1,pc2,pc3, bc0,bc1,bc2,bc3, rc0,rc1,rc2,rc3)
    STORE_QUAD(cD, pd0,pd1,pd2,pd3, bd0,bd1,bd2,bd3, rd0,rd1,rd2,rd3)
    __syncthreads();

    // dense flush (consecutive s -> mostly consecutive global addresses)
    int tcount = e1 - e0;
    for (int s2 = tid; s2 < tcount; s2 += STHREADS) {
        int b = bof[s2];
        binned[adj[b] + s2] = staged[s2];
    }
}

// per-bucket in-degree histogram in LDS -> dinv = rsqrt(deg+1); w = dinv * u
__global__ __launch_bounds__(CTHREADS, 8)
void degree_dinv_k(const unsigned int* __restrict__ binned,
                   const int* __restrict__ cursor,
                   const float* __restrict__ u,
                   float* __restrict__ dinv, float* __restrict__ w, int n) {
    __shared__ int cnt[RNODES];
    int tid = threadIdx.x, b = blockIdx.x;
    if (tid < RNODES) cnt[tid] = 0;
    __syncthreads();
    size_t s0 = (size_t)b * BCAP;
    int c = cursor[b];
    if (c > BCAP) c = BCAP;
    int nvec = c >> 2;
    // up to 1536 quads over 512 threads: 3 named groups, then scalar tail
    uint4 pA, pB, pC;
    bool aA = tid < nvec, aB = tid + CTHREADS < nvec, aC = tid + 2*CTHREADS < nvec;
    if (aA) pA = *reinterpret_cast<const uint4*>(binned + s0 + 4 * (size_t)tid);
    if (aB) pB = *reinterpret_cast<const uint4*>(binned + s0 + 4 * (size_t)(tid + CTHREADS));
    if (aC) pC = *reinterpret_cast<const uint4*>(binned + s0 + 4 * (size_t)(tid + 2*CTHREADS));
    if (aA) {
        atomicAdd(&cnt[pA.x >> 17], 1); atomicAdd(&cnt[pA.y >> 17], 1);
        atomicAdd(&cnt[pA.z >> 17], 1); atomicAdd(&cnt[pA.w >> 17], 1);
    }
    if (aB) {
        atomicAdd(&cnt[pB.x >> 17], 1); atomicAdd(&cnt[pB.y >> 17], 1);
        atomicAdd(&cnt[pB.z >> 17], 1); atomicAdd(&cnt[pB.w >> 17], 1);
    }
    if (aC) {
        atomicAdd(&cnt[pC.x >> 17], 1); atomicAdd(&cnt[pC.y >> 17], 1);
        atomicAdd(&cnt[pC.z >> 17], 1); atomicAdd(&cnt[pC.w >> 17], 1);
    }
    int i = 4 * nvec + tid;
    if (i < c) atomicAdd(&cnt[binned[s0 + i] >> 17], 1);
    __syncthreads();
    int g = (b << RSHIFT) + tid;
    if (tid < RNODES && g < n) {
        float d = rsqrtf((float)(cnt[tid] + 1));
        dinv[g] = d;
        w[g] = d * u[g];
    }
}

// v = c1 + dinv*(sum of w[src]) + dinv^2*u ; wb = dinv*v
__global__ __launch_bounds__(CTHREADS, 8)
void conv_mid_k(const unsigned int* __restrict__ binned,
                const int* __restrict__ cursor,
                const float* __restrict__ w, const float* __restrict__ dinv,
                const float* __restrict__ u, const float* __restrict__ sc,
                float* __restrict__ v, float* __restrict__ wb, int n) {
    __shared__ float acc[RNODES];
    int tid = threadIdx.x, b = blockIdx.x;
    if (tid < RNODES) acc[tid] = 0.f;
    __syncthreads();
    size_t s0 = (size_t)b * BCAP;
    int cnt = cursor[b];
    if (cnt > BCAP) cnt = BCAP;
    int nvec = cnt >> 2;
    uint4 pA, pB, pC;
    bool aA = tid < nvec, aB = tid + CTHREADS < nvec, aC = tid + 2*CTHREADS < nvec;
    if (aA) pA = *reinterpret_cast<const uint4*>(binned + s0 + 4 * (size_t)tid);
    if (aB) pB = *reinterpret_cast<const uint4*>(binned + s0 + 4 * (size_t)(tid + CTHREADS));
    if (aC) pC = *reinterpret_cast<const uint4*>(binned + s0 + 4 * (size_t)(tid + 2*CTHREADS));
    float wa0=0,wa1=0,wa2=0,wa3=0, wb0=0,wb1=0,wb2=0,wb3=0, wc0=0,wc1=0,wc2=0,wc3=0;
    if (aA) { wa0=w[pA.x & 0x1FFFF]; wa1=w[pA.y & 0x1FFFF]; wa2=w[pA.z & 0x1FFFF]; wa3=w[pA.w & 0x1FFFF]; }
    if (aB) { wb0=w[pB.x & 0x1FFFF]; wb1=w[pB.y & 0x1FFFF]; wb2=w[pB.z & 0x1FFFF]; wb3=w[pB.w & 0x1FFFF]; }
    if (aC) { wc0=w[pC.x & 0x1FFFF]; wc1=w[pC.y & 0x1FFFF]; wc2=w[pC.z & 0x1FFFF]; wc3=w[pC.w & 0x1FFFF]; }
    if (aA) {
        atomicAdd(&acc[pA.x >> 17], wa0); atomicAdd(&acc[pA.y >> 17], wa1);
        atomicAdd(&acc[pA.z >> 17], wa2); atomicAdd(&acc[pA.w >> 17], wa3);
    }
    if (aB) {
        atomicAdd(&acc[pB.x >> 17], wb0); atomicAdd(&acc[pB.y >> 17], wb1);
        atomicAdd(&acc[pB.z >> 17], wb2); atomicAdd(&acc[pB.w >> 17], wb3);
    }
    if (aC) {
        atomicAdd(&acc[pC.x >> 17], wc0); atomicAdd(&acc[pC.y >> 17], wc1);
        atomicAdd(&acc[pC.z >> 17], wc2); atomicAdd(&acc[pC.w >> 17], wc3);
    }
    int i = 4 * nvec + tid;
    if (i < cnt) { unsigned p = binned[s0 + i]; atomicAdd(&acc[p >> 17], w[p & 0x1FFFF]); }
    __syncthreads();
    int g = (b << RSHIFT) + tid;
    if (tid < RNODES && g < n) {
        float di = dinv[g];
        float val = sc[0] + di * acc[tid] + di * di * u[g];
        v[g] = val;
        wb[g] = di * val;
    }
}

// t = c2 + dinv*sum + dinv^2*v, then segmented pool by sorted batch id
__global__ __launch_bounds__(CTHREADS, 8)
void conv_final_k(const unsigned int* __restrict__ binned,
                  const int* __restrict__ cursor,
                  const float* __restrict__ wbv, const float* __restrict__ dinv,
                  const float* __restrict__ v, const float* __restrict__ sc,
                  const int* __restrict__ batch, float* __restrict__ out, int n) {
    __shared__ float acc[RNODES];
    __shared__ float tbuf[RNODES];
    __shared__ int gbuf[RNODES];
    int tid = threadIdx.x, b = blockIdx.x;
    if (tid < RNODES) acc[tid] = 0.f;
    __syncthreads();
    size_t s0 = (size_t)b * BCAP;
    int cnt = cursor[b];
    if (cnt > BCAP) cnt = BCAP;
    int nvec = cnt >> 2;
    uint4 pA, pB, pC;
    bool aA = tid < nvec, aB = tid + CTHREADS < nvec, aC = tid + 2*CTHREADS < nvec;
    if (aA) pA = *reinterpret_cast<const uint4*>(binned + s0 + 4 * (size_t)tid);
    if (aB) pB = *reinterpret_cast<const uint4*>(binned + s0 + 4 * (size_t)(tid + CTHREADS));
    if (aC) pC = *reinterpret_cast<const uint4*>(binned + s0 + 4 * (size_t)(tid + 2*CTHREADS));
    float wa0=0,wa1=0,wa2=0,wa3=0, wb0=0,wb1=0,wb2=0,wb3=0, wc0=0,wc1=0,wc2=0,wc3=0;
    if (aA) { wa0=wbv[pA.x & 0x1FFFF]; wa1=wbv[pA.y & 0x1FFFF]; wa2=wbv[pA.z & 0x1FFFF]; wa3=wbv[pA.w & 0x1FFFF]; }
    if (aB) { wb0=wbv[pB.x & 0x1FFFF]; wb1=wbv[pB.y & 0x1FFFF]; wb2=wbv[pB.z & 0x1FFFF]; wb3=wbv[pB.w & 0x1FFFF]; }
    if (aC) { wc0=wbv[pC.x & 0x1FFFF]; wc1=wbv[pC.y & 0x1FFFF]; wc2=wbv[pC.z & 0x1FFFF]; wc3=wbv[pC.w & 0x1FFFF]; }
    if (aA) {
        atomicAdd(&acc[pA.x >> 17], wa0); atomicAdd(&acc[pA.y >> 17], wa1);
        atomicAdd(&acc[pA.z >> 17], wa2); atomicAdd(&acc[pA.w >> 17], wa3);
    }
    if (aB) {
        atomicAdd(&acc[pB.x >> 17], wb0); atomicAdd(&acc[pB.y >> 17], wb1);
        atomicAdd(&acc[pB.z >> 17], wb2); atomicAdd(&acc[pB.w >> 17], wb3);
    }
    if (aC) {
        atomicAdd(&acc[pC.x >> 17], wc0); atomicAdd(&acc[pC.y >> 17], wc1);
        atomicAdd(&acc[pC.z >> 17], wc2); atomicAdd(&acc[pC.w >> 17], wc3);
    }
    int i = 4 * nvec + tid;
    if (i < cnt) { unsigned p = binned[s0 + i]; atomicAdd(&acc[p >> 17], wbv[p & 0x1FFFF]); }
    __syncthreads();
    int g = (b << RSHIFT) + tid;
    float tval = 0.f; int gid = -1;
    if (tid < RNODES && g < n) {
        float di = dinv[g];
        tval = sc[1] + di * acc[tid] + di * di * v[g];
        gid = batch[g];
    }
    if (tid < RNODES) { tbuf[tid] = tval; gbuf[tid] = gid; }
    __syncthreads();
    if (tid < RNODES && g < n) {
        bool head = (tid == 0) || (gbuf[tid - 1] != gid);
        if (head) {
            float s = 0.f;
            int i2 = tid;
            while (i2 < RNODES && gbuf[i2] == gid) { s += tbuf[i2]; ++i2; }
            atomicAdd(&out[gid], s);
        }
    }
}

extern "C" void kernel_launch(void* const* d_in, const int* in_sizes, int n_in,
                              void* d_out, int out_size, void* d_ws, size_t ws_size,
                              hipStream_t stream)
{
    const float* x    = (const float*)d_in[0];
    const int*   ei   = (const int*)d_in[1];
    const int*   batch= (const int*)d_in[2];
    const float* W1   = (const float*)d_in[3];
    const float* b1   = (const float*)d_in[4];
    const float* W2   = (const float*)d_in[5];
    const float* b2   = (const float*)d_in[6];
    const float* Wf1  = (const float*)d_in[7];
    const float* bf1  = (const float*)d_in[8];
    const float* Wf2  = (const float*)d_in[9];
    const float* bf2  = (const float*)d_in[10];
    const float* Wf3  = (const float*)d_in[11];
    const float* bf3  = (const float*)d_in[12];
    const float* Wo   = (const float*)d_in[13];
    const float* bo   = (const float*)d_in[14];
    float* out = (float*)d_out;

    const int n = in_sizes[0] / 64;
    const int E = in_sizes[1] / 2;
    const int G = out_size;
    const int* src = ei;
    const int* dst = ei + E;
    const int nb = (n + RNODES - 1) >> RSHIFT;

    // workspace layout (element offsets, all blocks 16B-aligned)
    float* ws_f = (float*)d_ws;
    int*   ws_i = (int*)d_ws;
    float* w1c    = ws_f;                    // 64
    float* sc     = ws_f + 64;               // 3 (+pad to 128)
    int*   cursor = ws_i + 128;              // NB_MAX
    size_t off_u  = 128 + (size_t)NB_MAX;
    float* u      = ws_f + off_u;            // n
    float* dinv   = u + n;                   // n
    float* w      = dinv + n;                // n
    float* v      = w + n;                   // n
    float* wb     = v + n;                   // n
    size_t off_b  = off_u + 5*(size_t)n;
    off_b = (off_b + 3) & ~(size_t)3;
    unsigned int* binned = (unsigned int*)(ws_f + off_b);   // nb * BCAP

    const int NT = (E + STAGE_CAP - 1) / STAGE_CAP;   // scatter tiles
    const int npb = (n + NT - 1) / NT;                // nodes per tile for u

    hipLaunchKernelGGL(collapse_weights_k, dim3(1), dim3(64), 0, stream,
                       W1, b1, W2, b2, Wf1, bf1, Wf2, bf2, Wf3, bf3, Wo, bo,
                       w1c, sc, cursor, out, G);
    hipLaunchKernelGGL(scatter_u_k, dim3(NT), dim3(STHREADS), 0, stream,
                       x, w1c, u, src, dst, E, n, npb, nb, cursor, binned);
    hipLaunchKernelGGL(degree_dinv_k, dim3(nb), dim3(CTHREADS), 0, stream,
                       binned, cursor, u, dinv, w, n);
    hipLaunchKernelGGL(conv_mid_k, dim3(nb), dim3(CTHREADS), 0, stream,
                       binned, cursor, w, dinv, u, sc, v, wb, n);
    hipLaunchKernelGGL(conv_final_k, dim3(nb), dim3(CTHREADS), 0, stream,
                       binned, cursor, wb, dinv, v, sc, batch, out, n);
}

// Round 7
// 206.503 us; speedup vs baseline: 1.0807x; 1.0022x over previous
//
#include <hip/hip_runtime.h>

// GCN edge predictor, collapsed to scalar-per-node linear algebra:
//   u_i = x_i . w1c ;  v = A u + c1 ;  t = A v + c2 ;  out[g] = sum_g t + c0
//   A = D^-1/2 (Adj + I) D^-1/2
// R11: node-sorted buckets -> atomic-free conv passes.
//   R10 plateau diagnosis: 3 passes x 4096 LDS atomicAdds/block onto 128
//   words (32-way same-address collisions) serialize; gathers are L2-hits.
//   sort_dinv_k: bucket -> LDS, per-node count (atomics), prefix, rank-
//   scatter (atomics), write node-sorted bucket back + offG/dinv/w.
//   conv_*: 4 lanes/node read the node's CONTIGUOUS segment, register
//   accumulate, shfl-reduce. No LDS atomics, ~1KB LDS, 32 waves/CU.
//   Pipeline: collapse, scatter+u, sort_dinv, conv_mid, conv_final (5).

#define RSHIFT 7
#define RNODES 128           // nodes per bucket
#define NB_MAX 1024          // max buckets (n <= 131072; src fits 17 bits)
#define STHREADS 512         // scatter threads
#define CTHREADS 512         // conv/sort threads
#define STAGE_CAP 8192       // edges per tile (16 per thread)
#define BCAP 6144            // per-bucket slab capacity (mean ~4092, +32 sigma)

__global__ void collapse_weights_k(
    const float* __restrict__ W1, const float* __restrict__ b1,
    const float* __restrict__ W2, const float* __restrict__ b2,
    const float* __restrict__ Wf1, const float* __restrict__ bf1,
    const float* __restrict__ Wf2, const float* __restrict__ bf2,
    const float* __restrict__ Wf3, const float* __restrict__ bf3,
    const float* __restrict__ Wo, const float* __restrict__ bo,
    float* __restrict__ w1c, float* __restrict__ sc,
    int* __restrict__ cursor, float* __restrict__ out, int G)
{
    __shared__ float wo[10], w3[20], w2[30], w1[50], w2c[60];
    __shared__ float c0s;
    const int t = threadIdx.x;  // 64 threads
    for (int b = t; b < NB_MAX; b += 64) cursor[b] = 0;
    if (t < 10) wo[t] = Wo[t];
    __syncthreads();
    if (t < 20) { float s = 0.f; for (int j = 0; j < 10; ++j) s += Wf3[t*10+j]*wo[j]; w3[t] = s; }
    __syncthreads();
    if (t < 30) { float s = 0.f; for (int j = 0; j < 20; ++j) s += Wf2[t*20+j]*w3[j]; w2[t] = s; }
    __syncthreads();
    if (t < 50) { float s = 0.f; for (int j = 0; j < 30; ++j) s += Wf1[t*30+j]*w2[j]; w1[t] = s; }
    __syncthreads();
    if (t < 60) { float s = 0.f; for (int j = 0; j < 50; ++j) s += W2[t*50+j]*w1[j]; w2c[t] = s; }
    __syncthreads();
    { float s = 0.f; for (int j = 0; j < 60; ++j) s += W1[t*60+j]*w2c[j]; w1c[t] = s; }
    if (t == 0) {
        float c1 = 0.f; for (int j = 0; j < 60; ++j) c1 += b1[j]*w2c[j];
        float c2 = 0.f; for (int j = 0; j < 50; ++j) c2 += b2[j]*w1[j];
        float c0 = bo[0];
        for (int j = 0; j < 30; ++j) c0 += bf1[j]*w2[j];
        for (int j = 0; j < 20; ++j) c0 += bf2[j]*w3[j];
        for (int j = 0; j < 10; ++j) c0 += bf3[j]*wo[j];
        sc[0] = c1; sc[1] = c2; sc[2] = c0;
        c0s = c0;
    }
    __syncthreads();
    for (int g = t; g < G; g += 64) out[g] = c0s;
}

// one quad-group of the scatter staging, all state in caller-named scalars
#define LOAD_QUAD(ii, cc, P0, P1, P2, P3, B0, B1, B2, B3, R0, R1, R2, R3)     \
    if (cc == 4) {                                                            \
        int4 s4 = *reinterpret_cast<const int4*>(src + ii);                   \
        int4 d4 = *reinterpret_cast<const int4*>(dst + ii);                   \
        P0 = (unsigned)s4.x | ((unsigned)(d4.x & (RNODES-1)) << 17);          \
        P1 = (unsigned)s4.y | ((unsigned)(d4.y & (RNODES-1)) << 17);          \
        P2 = (unsigned)s4.z | ((unsigned)(d4.z & (RNODES-1)) << 17);          \
        P3 = (unsigned)s4.w | ((unsigned)(d4.w & (RNODES-1)) << 17);          \
        B0 = d4.x >> RSHIFT; B1 = d4.y >> RSHIFT;                             \
        B2 = d4.z >> RSHIFT; B3 = d4.w >> RSHIFT;                             \
        R0 = atomicAdd(&hist[B0], 1);                                         \
        R1 = atomicAdd(&hist[B1], 1);                                         \
        R2 = atomicAdd(&hist[B2], 1);                                         \
        R3 = atomicAdd(&hist[B3], 1);                                         \
    } else {                                                                  \
        if (cc > 0) { int s=src[ii],   d=dst[ii];   P0=(unsigned)s|((unsigned)(d&(RNODES-1))<<17); B0=d>>RSHIFT; R0=atomicAdd(&hist[B0],1); } \
        if (cc > 1) { int s=src[ii+1], d=dst[ii+1]; P1=(unsigned)s|((unsigned)(d&(RNODES-1))<<17); B1=d>>RSHIFT; R1=atomicAdd(&hist[B1],1); } \
        if (cc > 2) { int s=src[ii+2], d=dst[ii+2]; P2=(unsigned)s|((unsigned)(d&(RNODES-1))<<17); B2=d>>RSHIFT; R2=atomicAdd(&hist[B2],1); } \
    }

#define STORE_QUAD(cc, P0, P1, P2, P3, B0, B1, B2, B3, R0, R1, R2, R3)        \
    if (cc > 0) { int s2 = tbase[B0] + R0; staged[s2] = P0; bof[s2] = (unsigned short)B0; } \
    if (cc > 1) { int s2 = tbase[B1] + R1; staged[s2] = P1; bof[s2] = (unsigned short)B1; } \
    if (cc > 2) { int s2 = tbase[B2] + R2; staged[s2] = P2; bof[s2] = (unsigned short)B2; } \
    if (cc > 3) { int s2 = tbase[B3] + R3; staged[s2] = P3; bof[s2] = (unsigned short)B3; }

// Fused: (A) u for this block's node slice; (B) scatter tile bx into slabs.
__global__ __launch_bounds__(STHREADS, 4)
void scatter_u_k(const float* __restrict__ x, const float* __restrict__ w1c,
                 float* __restrict__ u,
                 const int* __restrict__ src, const int* __restrict__ dst,
                 int E, int n, int npb, int nb,
                 int* __restrict__ cursor, unsigned int* __restrict__ binned) {
    __shared__ int hist[NB_MAX];
    __shared__ int tbase[NB_MAX];
    __shared__ int adj[NB_MAX];
    __shared__ int sums[STHREADS];
    __shared__ unsigned int staged[STAGE_CAP];
    __shared__ unsigned short bof[STAGE_CAP];
    const int tid = threadIdx.x;
    const int bx = blockIdx.x;

    // ---- (A) u for nodes [bx*npb, bx*npb+npb) ----
    {
        const int grp = tid >> 4, sub = tid & 15;
        float4 wv = *reinterpret_cast<const float4*>(w1c + sub * 4);
        int base = bx * npb;
        for (int p = 0; p * 32 < npb; ++p) {
            int nl = p * 32 + grp;
            int g = base + nl;
            bool ok = (nl < npb) && (g < n);
            float val = 0.f;
            if (ok) {
                float4 xv = *reinterpret_cast<const float4*>(
                    x + (size_t)g * 64 + sub * 4);
                val = xv.x*wv.x + xv.y*wv.y + xv.z*wv.z + xv.w*wv.w;
            }
            val += __shfl_down(val, 8, 16);
            val += __shfl_down(val, 4, 16);
            val += __shfl_down(val, 2, 16);
            val += __shfl_down(val, 1, 16);
            if (ok && sub == 0) u[g] = val;
        }
    }

    // ---- (B) scatter tile bx: 16 edges/thread in 4 named quad groups ----
    hist[tid] = 0; hist[tid + STHREADS] = 0;
    __syncthreads();
    int e0 = bx * STAGE_CAP;
    int e1 = e0 + STAGE_CAP; if (e1 > E) e1 = E;

    unsigned pa0=0,pa1=0,pa2=0,pa3=0, pb0=0,pb1=0,pb2=0,pb3=0;
    unsigned pc0=0,pc1=0,pc2=0,pc3=0, pd0=0,pd1=0,pd2=0,pd3=0;
    int ba0=0,ba1=0,ba2=0,ba3=0, bb0=0,bb1=0,bb2=0,bb3=0;
    int bc0=0,bc1=0,bc2=0,bc3=0, bd0=0,bd1=0,bd2=0,bd3=0;
    int ra0=0,ra1=0,ra2=0,ra3=0, rb0=0,rb1=0,rb2=0,rb3=0;
    int rc0=0,rc1=0,rc2=0,rc3=0, rd0=0,rd1=0,rd2=0,rd3=0;

    int iA = e0 + tid * 4;
    int iB = iA + STHREADS * 4;
    int iC = iB + STHREADS * 4;
    int iD = iC + STHREADS * 4;
    int cA = e1 - iA; if (cA > 4) cA = 4; if (cA < 0) cA = 0;
    int cB = e1 - iB; if (cB > 4) cB = 4; if (cB < 0) cB = 0;
    int cC = e1 - iC; if (cC > 4) cC = 4; if (cC < 0) cC = 0;
    int cD = e1 - iD; if (cD > 4) cD = 4; if (cD < 0) cD = 0;

    LOAD_QUAD(iA, cA, pa0,pa1,pa2,pa3, ba0,ba1,ba2,ba3, ra0,ra1,ra2,ra3)
    LOAD_QUAD(iB, cB, pb0,pb1,pb2,pb3, bb0,bb1,bb2,bb3, rb0,rb1,rb2,rb3)
    LOAD_QUAD(iC, cC, pc0,pc1,pc2,pc3, bc0,bc1,bc2,bc3, rc0,rc1,rc2,rc3)
    LOAD_QUAD(iD, cD, pd0,pd1,pd2,pd3, bd0,bd1,bd2,bd3, rd0,rd1,rd2,rd3)
    __syncthreads();

    // block-exclusive scan of hist[0..1023] (2 slots per thread)
    int h0 = hist[2*tid], h1 = hist[2*tid+1];
    int pair = h0 + h1;
    sums[tid] = pair;
    __syncthreads();
    for (int off = 1; off < STHREADS; off <<= 1) {
        int a = (tid >= off) ? sums[tid - off] : 0;
        __syncthreads();
        sums[tid] += a;
        __syncthreads();
    }
    int excl = sums[tid] - pair;
    tbase[2*tid] = excl;
    tbase[2*tid+1] = excl + h0;
    // reserve this tile's segment in each bucket's slab
    {
        int b0 = 2*tid, b1 = 2*tid + 1;
        if (b0 < nb && h0 > 0) {
            int r = atomicAdd(&cursor[b0], h0);
            adj[b0] = b0 * BCAP + r - excl;
        }
        if (b1 < nb && h1 > 0) {
            int r = atomicAdd(&cursor[b1], h1);
            adj[b1] = b1 * BCAP + r - (excl + h0);
        }
    }
    __syncthreads();

    STORE_QUAD(cA, pa0,pa1,pa2,pa3, ba0,ba1,ba2,ba3, ra0,ra1,ra2,ra3)
    STORE_QUAD(cB, pb0,pb1,pb2,pb3, bb0,bb1,bb2,bb3, rb0,rb1,rb2,rb3)
    STORE_QUAD(cC, pc0,pc1,pc2,pc3, bc0,bc1,bc2,bc3, rc0,rc1,rc2,rc3)
    STORE_QUAD(cD, pd0,pd1,pd2,pd3, bd0,bd1,bd2,bd3, rd0,rd1,rd2,rd3)
    __syncthreads();

    // dense flush (consecutive s -> mostly consecutive global addresses)
    int tcount = e1 - e0;
    for (int s2 = tid; s2 < tcount; s2 += STHREADS) {
        int b = bof[s2];
        binned[adj[b] + s2] = staged[s2];
    }
}

// Sort bucket edges by destination node in LDS; emit node-sorted bucket,
// per-node within-bucket offsets, dinv = rsqrt(deg+1), w = dinv*u.
__global__ __launch_bounds__(CTHREADS, 4)
void sort_dinv_k(unsigned int* __restrict__ binned,
                 const int* __restrict__ cursor,
                 const float* __restrict__ u,
                 float* __restrict__ dinv, float* __restrict__ w,
                 int* __restrict__ offG, int n) {
    __shared__ unsigned eIn[BCAP];    // 24 KB
    __shared__ unsigned eOut[BCAP];   // 24 KB
    __shared__ int cnt[RNODES];
    __shared__ int off[RNODES];
    __shared__ int pos[RNODES];
    const int tid = threadIdx.x, b = blockIdx.x;
    if (tid < RNODES) cnt[tid] = 0;
    __syncthreads();
    size_t s0 = (size_t)b * BCAP;
    int c = cursor[b];
    if (c > BCAP) c = BCAP;
    int nvec = c >> 2;
    // load + count fused
    for (int k = tid; k < nvec; k += CTHREADS) {
        uint4 p = *reinterpret_cast<const uint4*>(binned + s0 + 4 * (size_t)k);
        eIn[4*k+0] = p.x; eIn[4*k+1] = p.y; eIn[4*k+2] = p.z; eIn[4*k+3] = p.w;
        atomicAdd(&cnt[p.x >> 17], 1);
        atomicAdd(&cnt[p.y >> 17], 1);
        atomicAdd(&cnt[p.z >> 17], 1);
        atomicAdd(&cnt[p.w >> 17], 1);
    }
    for (int i = 4 * nvec + tid; i < c; i += CTHREADS) {
        unsigned p = binned[s0 + i];
        eIn[i] = p;
        atomicAdd(&cnt[p >> 17], 1);
    }
    __syncthreads();
    // 128-entry exclusive scan (Hillis-Steele, block-wide syncs)
    int hval = (tid < RNODES) ? cnt[tid] : 0;
    if (tid < RNODES) off[tid] = hval;
    __syncthreads();
    for (int o = 1; o < RNODES; o <<= 1) {
        int a = 0;
        if (tid < RNODES && tid >= o) a = off[tid - o];
        __syncthreads();
        if (tid < RNODES) off[tid] += a;
        __syncthreads();
    }
    if (tid < RNODES) {
        int e = off[tid] - hval;   // exclusive
        off[tid] = e;
        pos[tid] = e;
    }
    __syncthreads();
    // rank + scatter into node-sorted order
    for (int i = tid; i < c; i += CTHREADS) {
        unsigned p = eIn[i];
        int r = atomicAdd(&pos[p >> 17], 1);
        eOut[r] = p;
    }
    __syncthreads();
    // write back (vectorized) + per-node outputs
    for (int k = tid; k < nvec; k += CTHREADS) {
        uint4 p;
        p.x = eOut[4*k+0]; p.y = eOut[4*k+1]; p.z = eOut[4*k+2]; p.w = eOut[4*k+3];
        *reinterpret_cast<uint4*>(binned + s0 + 4 * (size_t)k) = p;
    }
    for (int i = 4 * nvec + tid; i < c; i += CTHREADS)
        binned[s0 + i] = eOut[i];
    if (tid < RNODES) {
        int g = (b << RSHIFT) + tid;
        if (g < n) {
            float d = rsqrtf((float)(cnt[tid] + 1));
            dinv[g] = d;
            w[g] = d * u[g];
            offG[g] = off[tid];
        }
    }
}

// v = c1 + dinv*(sum of w[src] over node's contiguous segment) + dinv^2*u
// 4 lanes per node, register accumulation, shfl reduce. No LDS atomics.
__global__ __launch_bounds__(CTHREADS, 8)
void conv_mid_k(const unsigned int* __restrict__ binned,
                const int* __restrict__ cursor, const int* __restrict__ offG,
                const float* __restrict__ w, const float* __restrict__ dinv,
                const float* __restrict__ u, const float* __restrict__ sc,
                float* __restrict__ v, float* __restrict__ wb, int n) {
    __shared__ int off_s[RNODES + 1];
    int tid = threadIdx.x, b = blockIdx.x;
    size_t s0 = (size_t)b * BCAP;
    int c = cursor[b];
    if (c > BCAP) c = BCAP;
    if (tid < RNODES) {
        int g = (b << RSHIFT) + tid;
        off_s[tid] = (g < n) ? offG[g] : c;
    }
    if (tid == 0) off_s[RNODES] = c;
    __syncthreads();
    int node = tid >> 2, sub = tid & 3;
    int g = (b << RSHIFT) + node;
    int o0 = off_s[node], o1 = off_s[node + 1];
    float s = 0.f;
    for (int k = o0 + sub; k < o1; k += 4) {
        unsigned p = binned[s0 + k];
        s += w[p & 0x1FFFF];
    }
    s += __shfl_xor(s, 1, 4);
    s += __shfl_xor(s, 2, 4);
    if (sub == 0 && g < n) {
        float di = dinv[g];
        float val = sc[0] + di * s + di * di * u[g];
        v[g] = val;
        wb[g] = di * val;
    }
}

// t = c2 + dinv*sum + dinv^2*v, then segmented pool by sorted batch id
__global__ __launch_bounds__(CTHREADS, 8)
void conv_final_k(const unsigned int* __restrict__ binned,
                  const int* __restrict__ cursor, const int* __restrict__ offG,
                  const float* __restrict__ wbv, const float* __restrict__ dinv,
                  const float* __restrict__ v, const float* __restrict__ sc,
                  const int* __restrict__ batch, float* __restrict__ out, int n) {
    __shared__ int off_s[RNODES + 1];
    __shared__ float tbuf[RNODES];
    __shared__ int gbuf[RNODES];
    int tid = threadIdx.x, b = blockIdx.x;
    size_t s0 = (size_t)b * BCAP;
    int c = cursor[b];
    if (c > BCAP) c = BCAP;
    if (tid < RNODES) {
        int g = (b << RSHIFT) + tid;
        off_s[tid] = (g < n) ? offG[g] : c;
    }
    if (tid == 0) off_s[RNODES] = c;
    __syncthreads();
    int node = tid >> 2, sub = tid & 3;
    int g = (b << RSHIFT) + node;
    int o0 = off_s[node], o1 = off_s[node + 1];
    float s = 0.f;
    for (int k = o0 + sub; k < o1; k += 4) {
        unsigned p = binned[s0 + k];
        s += wbv[p & 0x1FFFF];
    }
    s += __shfl_xor(s, 1, 4);
    s += __shfl_xor(s, 2, 4);
    if (sub == 0) {
        float tval = 0.f; int gid = -1;
        if (g < n) {
            float di = dinv[g];
            tval = sc[1] + di * s + di * di * v[g];
            gid = batch[g];
        }
        tbuf[node] = tval;
        gbuf[node] = gid;
    }
    __syncthreads();
    if (tid < RNODES) {
        int g2 = (b << RSHIFT) + tid;
        if (g2 < n) {
            int gid = gbuf[tid];
            bool head = (tid == 0) || (gbuf[tid - 1] != gid);
            if (head) {
                float sum = 0.f;
                int i2 = tid;
                while (i2 < RNODES && gbuf[i2] == gid) { sum += tbuf[i2]; ++i2; }
                atomicAdd(&out[gid], sum);
            }
        }
    }
}

extern "C" void kernel_launch(void* const* d_in, const int* in_sizes, int n_in,
                              void* d_out, int out_size, void* d_ws, size_t ws_size,
                              hipStream_t stream)
{
    const float* x    = (const float*)d_in[0];
    const int*   ei   = (const int*)d_in[1];
    const int*   batch= (const int*)d_in[2];
    const float* W1   = (const float*)d_in[3];
    const float* b1   = (const float*)d_in[4];
    const float* W2   = (const float*)d_in[5];
    const float* b2   = (const float*)d_in[6];
    const float* Wf1  = (const float*)d_in[7];
    const float* bf1  = (const float*)d_in[8];
    const float* Wf2  = (const float*)d_in[9];
    const float* bf2  = (const float*)d_in[10];
    const float* Wf3  = (const float*)d_in[11];
    const float* bf3  = (const float*)d_in[12];
    const float* Wo   = (const float*)d_in[13];
    const float* bo   = (const float*)d_in[14];
    float* out = (float*)d_out;

    const int n = in_sizes[0] / 64;
    const int E = in_sizes[1] / 2;
    const int G = out_size;
    const int* src = ei;
    const int* dst = ei + E;
    const int nb = (n + RNODES - 1) >> RSHIFT;

    // workspace layout (element offsets, all blocks 16B-aligned)
    float* ws_f = (float*)d_ws;
    int*   ws_i = (int*)d_ws;
    float* w1c    = ws_f;                    // 64
    float* sc     = ws_f + 64;               // 3 (+pad to 128)
    int*   cursor = ws_i + 128;              // NB_MAX
    size_t off_u  = 128 + (size_t)NB_MAX;
    float* u      = ws_f + off_u;            // n
    float* dinv   = u + n;                   // n
    float* w      = dinv + n;                // n
    float* v      = w + n;                   // n
    float* wb     = v + n;                   // n
    int*   offG   = ws_i + off_u + 5*(size_t)n;   // n
    size_t off_b  = off_u + 6*(size_t)n;
    off_b = (off_b + 3) & ~(size_t)3;
    unsigned int* binned = (unsigned int*)(ws_f + off_b);   // nb * BCAP

    const int NT = (E + STAGE_CAP - 1) / STAGE_CAP;   // scatter tiles
    const int npb = (n + NT - 1) / NT;                // nodes per tile for u

    hipLaunchKernelGGL(collapse_weights_k, dim3(1), dim3(64), 0, stream,
                       W1, b1, W2, b2, Wf1, bf1, Wf2, bf2, Wf3, bf3, Wo, bo,
                       w1c, sc, cursor, out, G);
    hipLaunchKernelGGL(scatter_u_k, dim3(NT), dim3(STHREADS), 0, stream,
                       x, w1c, u, src, dst, E, n, npb, nb, cursor, binned);
    hipLaunchKernelGGL(sort_dinv_k, dim3(nb), dim3(CTHREADS), 0, stream,
                       binned, cursor, u, dinv, w, offG, n);
    hipLaunchKernelGGL(conv_mid_k, dim3(nb), dim3(CTHREADS), 0, stream,
                       binned, cursor, offG, w, dinv, u, sc, v, wb, n);
    hipLaunchKernelGGL(conv_final_k, dim3(nb), dim3(CTHREADS), 0, stream,
                       binned, cursor, offG, wb, dinv, v, sc, batch, out, n);
}

// Round 8
// 204.671 us; speedup vs baseline: 1.0903x; 1.0089x over previous
//
#include <hip/hip_runtime.h>

// GCN edge predictor, collapsed to scalar-per-node linear algebra:
//   u_i = x_i . w1c ;  v = A u + c1 ;  t = A v + c2 ;  out[g] = sum_g t + c0
//   A = D^-1/2 (Adj + I) D^-1/2
// R12: dispatch-count attack. R8/R10/R11 all ~205us regardless of kernel
//   internals -> each dispatch costs ~40us fixed; cut dispatches + serial
//   phases. Pipeline: memset(4KB cursor) + fused scatter (collapse-in-kernel,
//   u, hist, cursor-reserve, DIRECT global stores -- no block scan, no 48KB
//   staging LDS, no flush loop) + sort_dinv + conv_mid(+out init) +
//   conv_final. 4 kernels + microfill.

#define RSHIFT 7
#define RNODES 128           // nodes per bucket
#define NB_MAX 1024          // max buckets (n <= 131072; src fits 17 bits)
#define STHREADS 512         // scatter threads
#define CTHREADS 1024        // conv/sort threads
#define STAGE_CAP 8192       // edges per tile (16 per thread)
#define BCAP 6144            // per-bucket slab capacity (mean ~4092, +32 sigma)

// one quad-group of the scatter staging, all state in caller-named scalars
#define LOAD_QUAD(ii, cc, P0, P1, P2, P3, B0, B1, B2, B3, R0, R1, R2, R3)     \
    if (cc == 4) {                                                            \
        int4 s4 = *reinterpret_cast<const int4*>(src + ii);                   \
        int4 d4 = *reinterpret_cast<const int4*>(dst + ii);                   \
        P0 = (unsigned)s4.x | ((unsigned)(d4.x & (RNODES-1)) << 17);          \
        P1 = (unsigned)s4.y | ((unsigned)(d4.y & (RNODES-1)) << 17);          \
        P2 = (unsigned)s4.z | ((unsigned)(d4.z & (RNODES-1)) << 17);          \
        P3 = (unsigned)s4.w | ((unsigned)(d4.w & (RNODES-1)) << 17);          \
        B0 = d4.x >> RSHIFT; B1 = d4.y >> RSHIFT;                             \
        B2 = d4.z >> RSHIFT; B3 = d4.w >> RSHIFT;                             \
        R0 = atomicAdd(&hist[B0], 1);                                         \
        R1 = atomicAdd(&hist[B1], 1);                                         \
        R2 = atomicAdd(&hist[B2], 1);                                         \
        R3 = atomicAdd(&hist[B3], 1);                                         \
    } else {                                                                  \
        if (cc > 0) { int s=src[ii],   d=dst[ii];   P0=(unsigned)s|((unsigned)(d&(RNODES-1))<<17); B0=d>>RSHIFT; R0=atomicAdd(&hist[B0],1); } \
        if (cc > 1) { int s=src[ii+1], d=dst[ii+1]; P1=(unsigned)s|((unsigned)(d&(RNODES-1))<<17); B1=d>>RSHIFT; R1=atomicAdd(&hist[B1],1); } \
        if (cc > 2) { int s=src[ii+2], d=dst[ii+2]; P2=(unsigned)s|((unsigned)(d&(RNODES-1))<<17); B2=d>>RSHIFT; R2=atomicAdd(&hist[B2],1); } \
    }

// direct global store of one quad-group (fire-and-forget)
#define STOREG_QUAD(cc, P0, P1, P2, P3, B0, B1, B2, B3, R0, R1, R2, R3)       \
    if (cc > 0) binned[(size_t)B0 * BCAP + lbase[B0] + R0] = P0;              \
    if (cc > 1) binned[(size_t)B1 * BCAP + lbase[B1] + R1] = P1;              \
    if (cc > 2) binned[(size_t)B2 * BCAP + lbase[B2] + R2] = P2;              \
    if (cc > 3) binned[(size_t)B3 * BCAP + lbase[B3] + R3] = P3;

// Fused: weight collapse (block-redundant) + u + single-pass direct scatter.
__global__ __launch_bounds__(STHREADS, 4)
void scatter_k(const float* __restrict__ x,
               const int* __restrict__ src, const int* __restrict__ dst,
               const float* __restrict__ W1, const float* __restrict__ b1,
               const float* __restrict__ W2, const float* __restrict__ b2,
               const float* __restrict__ Wf1, const float* __restrict__ bf1,
               const float* __restrict__ Wf2, const float* __restrict__ bf2,
               const float* __restrict__ Wf3, const float* __restrict__ bf3,
               const float* __restrict__ Wo, const float* __restrict__ bo,
               float* __restrict__ u, float* __restrict__ scG,
               int E, int n, int npb, int nb,
               int* __restrict__ cursor, unsigned int* __restrict__ binned) {
    __shared__ int hist[NB_MAX];
    __shared__ int lbase[NB_MAX];
    __shared__ float wtmp[224];
    __shared__ float w1c_s[64];
    const int tid = threadIdx.x;
    const int bx = blockIdx.x;

    // ---- weight collapse (redundant per block; ~9K MACs) ----
    {
        float* wo  = wtmp;         // 10
        float* w3  = wtmp + 16;    // 20
        float* w2  = wtmp + 48;    // 30
        float* w1  = wtmp + 80;    // 50
        float* w2c = wtmp + 144;   // 60
        hist[tid] = 0; hist[tid + STHREADS] = 0;
        if (tid < 10) wo[tid] = Wo[tid];
        __syncthreads();
        if (tid < 20) { float s = 0.f; for (int j = 0; j < 10; ++j) s += Wf3[tid*10+j]*wo[j]; w3[tid] = s; }
        __syncthreads();
        if (tid < 30) { float s = 0.f; for (int j = 0; j < 20; ++j) s += Wf2[tid*20+j]*w3[j]; w2[tid] = s; }
        __syncthreads();
        if (tid < 50) { float s = 0.f; for (int j = 0; j < 30; ++j) s += Wf1[tid*30+j]*w2[j]; w1[tid] = s; }
        __syncthreads();
        if (tid < 60) { float s = 0.f; for (int j = 0; j < 50; ++j) s += W2[tid*50+j]*w1[j]; w2c[tid] = s; }
        __syncthreads();
        if (tid < 64) { float s = 0.f; for (int j = 0; j < 60; ++j) s += W1[tid*60+j]*w2c[j]; w1c_s[tid] = s; }
        if (bx == 0 && tid == 0) {
            float c1 = 0.f; for (int j = 0; j < 60; ++j) c1 += b1[j]*w2c[j];
            float c2 = 0.f; for (int j = 0; j < 50; ++j) c2 += b2[j]*w1[j];
            float c0 = bo[0];
            for (int j = 0; j < 30; ++j) c0 += bf1[j]*w2[j];
            for (int j = 0; j < 20; ++j) c0 += bf2[j]*w3[j];
            for (int j = 0; j < 10; ++j) c0 += bf3[j]*wo[j];
            scG[0] = c1; scG[1] = c2; scG[2] = c0;
        }
        __syncthreads();
    }

    // ---- u for nodes [bx*npb, bx*npb+npb) ----
    {
        const int grp = tid >> 4, sub = tid & 15;
        float4 wv = *reinterpret_cast<const float4*>(&w1c_s[sub * 4]);
        int base = bx * npb;
        for (int p = 0; p * 32 < npb; ++p) {
            int nl = p * 32 + grp;
            int g = base + nl;
            bool ok = (nl < npb) && (g < n);
            float val = 0.f;
            if (ok) {
                float4 xv = *reinterpret_cast<const float4*>(
                    x + (size_t)g * 64 + sub * 4);
                val = xv.x*wv.x + xv.y*wv.y + xv.z*wv.z + xv.w*wv.w;
            }
            val += __shfl_down(val, 8, 16);
            val += __shfl_down(val, 4, 16);
            val += __shfl_down(val, 2, 16);
            val += __shfl_down(val, 1, 16);
            if (ok && sub == 0) u[g] = val;
        }
    }

    // ---- scatter tile bx: 16 edges/thread, 4 named quad groups ----
    int e0 = bx * STAGE_CAP;
    int e1 = e0 + STAGE_CAP; if (e1 > E) e1 = E;

    unsigned pa0=0,pa1=0,pa2=0,pa3=0, pb0=0,pb1=0,pb2=0,pb3=0;
    unsigned pc0=0,pc1=0,pc2=0,pc3=0, pd0=0,pd1=0,pd2=0,pd3=0;
    int ba0=0,ba1=0,ba2=0,ba3=0, bb0=0,bb1=0,bb2=0,bb3=0;
    int bc0=0,bc1=0,bc2=0,bc3=0, bd0=0,bd1=0,bd2=0,bd3=0;
    int ra0=0,ra1=0,ra2=0,ra3=0, rb0=0,rb1=0,rb2=0,rb3=0;
    int rc0=0,rc1=0,rc2=0,rc3=0, rd0=0,rd1=0,rd2=0,rd3=0;

    int iA = e0 + tid * 4;
    int iB = iA + STHREADS * 4;
    int iC = iB + STHREADS * 4;
    int iD = iC + STHREADS * 4;
    int cA = e1 - iA; if (cA > 4) cA = 4; if (cA < 0) cA = 0;
    int cB = e1 - iB; if (cB > 4) cB = 4; if (cB < 0) cB = 0;
    int cC = e1 - iC; if (cC > 4) cC = 4; if (cC < 0) cC = 0;
    int cD = e1 - iD; if (cD > 4) cD = 4; if (cD < 0) cD = 0;

    LOAD_QUAD(iA, cA, pa0,pa1,pa2,pa3, ba0,ba1,ba2,ba3, ra0,ra1,ra2,ra3)
    LOAD_QUAD(iB, cB, pb0,pb1,pb2,pb3, bb0,bb1,bb2,bb3, rb0,rb1,rb2,rb3)
    LOAD_QUAD(iC, cC, pc0,pc1,pc2,pc3, bc0,bc1,bc2,bc3, rc0,rc1,rc2,rc3)
    LOAD_QUAD(iD, cD, pd0,pd1,pd2,pd3, bd0,bd1,bd2,bd3, rd0,rd1,rd2,rd3)
    __syncthreads();

    // reserve each bucket's slab segment for this tile (no block scan needed)
    {
        int b0 = tid, b1 = tid + STHREADS;
        int h0 = hist[b0], h1 = hist[b1];
        if (h0 > 0) lbase[b0] = atomicAdd(&cursor[b0], h0);
        if (h1 > 0) lbase[b1] = atomicAdd(&cursor[b1], h1);
    }
    __syncthreads();

    STOREG_QUAD(cA, pa0,pa1,pa2,pa3, ba0,ba1,ba2,ba3, ra0,ra1,ra2,ra3)
    STOREG_QUAD(cB, pb0,pb1,pb2,pb3, bb0,bb1,bb2,bb3, rb0,rb1,rb2,rb3)
    STOREG_QUAD(cC, pc0,pc1,pc2,pc3, bc0,bc1,bc2,bc3, rc0,rc1,rc2,rc3)
    STOREG_QUAD(cD, pd0,pd1,pd2,pd3, bd0,bd1,bd2,bd3, rd0,rd1,rd2,rd3)
}

// Sort bucket edges by destination node in LDS; emit node-sorted bucket,
// per-node within-bucket offsets, dinv = rsqrt(deg+1), w = dinv*u.
__global__ __launch_bounds__(CTHREADS, 2)
void sort_dinv_k(unsigned int* __restrict__ binned,
                 const int* __restrict__ cursor,
                 const float* __restrict__ u,
                 float* __restrict__ dinv, float* __restrict__ w,
                 int* __restrict__ offG, int n) {
    __shared__ unsigned eIn[BCAP];    // 24 KB
    __shared__ unsigned eOut[BCAP];   // 24 KB
    __shared__ int cnt[RNODES];
    __shared__ int off[RNODES];
    __shared__ int pos[RNODES];
    const int tid = threadIdx.x, b = blockIdx.x;
    if (tid < RNODES) cnt[tid] = 0;
    __syncthreads();
    size_t s0 = (size_t)b * BCAP;
    int c = cursor[b];
    if (c > BCAP) c = BCAP;
    int nvec = c >> 2;
    // load + count fused
    for (int k = tid; k < nvec; k += CTHREADS) {
        uint4 p = *reinterpret_cast<const uint4*>(binned + s0 + 4 * (size_t)k);
        eIn[4*k+0] = p.x; eIn[4*k+1] = p.y; eIn[4*k+2] = p.z; eIn[4*k+3] = p.w;
        atomicAdd(&cnt[p.x >> 17], 1);
        atomicAdd(&cnt[p.y >> 17], 1);
        atomicAdd(&cnt[p.z >> 17], 1);
        atomicAdd(&cnt[p.w >> 17], 1);
    }
    for (int i = 4 * nvec + tid; i < c; i += CTHREADS) {
        unsigned p = binned[s0 + i];
        eIn[i] = p;
        atomicAdd(&cnt[p >> 17], 1);
    }
    __syncthreads();
    // 128-entry exclusive scan (Hillis-Steele)
    int hval = (tid < RNODES) ? cnt[tid] : 0;
    if (tid < RNODES) off[tid] = hval;
    __syncthreads();
    for (int o = 1; o < RNODES; o <<= 1) {
        int a = 0;
        if (tid < RNODES && tid >= o) a = off[tid - o];
        __syncthreads();
        if (tid < RNODES) off[tid] += a;
        __syncthreads();
    }
    if (tid < RNODES) {
        int e = off[tid] - hval;   // exclusive
        off[tid] = e;
        pos[tid] = e;
    }
    __syncthreads();
    // rank + scatter into node-sorted order
    for (int i = tid; i < c; i += CTHREADS) {
        unsigned p = eIn[i];
        int r = atomicAdd(&pos[p >> 17], 1);
        eOut[r] = p;
    }
    __syncthreads();
    // write back (vectorized) + per-node outputs
    for (int k = tid; k < nvec; k += CTHREADS) {
        uint4 p;
        p.x = eOut[4*k+0]; p.y = eOut[4*k+1]; p.z = eOut[4*k+2]; p.w = eOut[4*k+3];
        *reinterpret_cast<uint4*>(binned + s0 + 4 * (size_t)k) = p;
    }
    for (int i = 4 * nvec + tid; i < c; i += CTHREADS)
        binned[s0 + i] = eOut[i];
    if (tid < RNODES) {
        int g = (b << RSHIFT) + tid;
        if (g < n) {
            float d = rsqrtf((float)(cnt[tid] + 1));
            dinv[g] = d;
            w[g] = d * u[g];
            offG[g] = off[tid];
        }
    }
}

// v = c1 + dinv*(sum of w[src] over node's contiguous segment) + dinv^2*u
// 8 lanes per node, register accumulation, shfl reduce. Also out[g] = c0.
__global__ __launch_bounds__(CTHREADS, 2)
void conv_mid_k(const unsigned int* __restrict__ binned,
                const int* __restrict__ cursor, const int* __restrict__ offG,
                const float* __restrict__ w, const float* __restrict__ dinv,
                const float* __restrict__ u, const float* __restrict__ sc,
                float* __restrict__ v, float* __restrict__ wb,
                float* __restrict__ out, int n, int G) {
    __shared__ int off_s[RNODES + 1];
    int tid = threadIdx.x, b = blockIdx.x;
    if (b == 0 && tid < G) out[tid] = sc[2];
    size_t s0 = (size_t)b * BCAP;
    int c = cursor[b];
    if (c > BCAP) c = BCAP;
    if (tid < RNODES) {
        int g = (b << RSHIFT) + tid;
        off_s[tid] = (g < n) ? offG[g] : c;
    }
    if (tid == 0) off_s[RNODES] = c;
    __syncthreads();
    int node = tid >> 3, sub = tid & 7;
    int g = (b << RSHIFT) + node;
    int o0 = off_s[node], o1 = off_s[node + 1];
    float s = 0.f;
    for (int k = o0 + sub; k < o1; k += 8) {
        unsigned p = binned[s0 + k];
        s += w[p & 0x1FFFF];
    }
    s += __shfl_xor(s, 1, 8);
    s += __shfl_xor(s, 2, 8);
    s += __shfl_xor(s, 4, 8);
    if (sub == 0 && g < n) {
        float di = dinv[g];
        float val = sc[0] + di * s + di * di * u[g];
        v[g] = val;
        wb[g] = di * val;
    }
}

// t = c2 + dinv*sum + dinv^2*v, then segmented pool by sorted batch id
__global__ __launch_bounds__(CTHREADS, 2)
void conv_final_k(const unsigned int* __restrict__ binned,
                  const int* __restrict__ cursor, const int* __restrict__ offG,
                  const float* __restrict__ wbv, const float* __restrict__ dinv,
                  const float* __restrict__ v, const float* __restrict__ sc,
                  const int* __restrict__ batch, float* __restrict__ out, int n) {
    __shared__ int off_s[RNODES + 1];
    __shared__ float tbuf[RNODES];
    __shared__ int gbuf[RNODES];
    int tid = threadIdx.x, b = blockIdx.x;
    size_t s0 = (size_t)b * BCAP;
    int c = cursor[b];
    if (c > BCAP) c = BCAP;
    if (tid < RNODES) {
        int g = (b << RSHIFT) + tid;
        off_s[tid] = (g < n) ? offG[g] : c;
    }
    if (tid == 0) off_s[RNODES] = c;
    __syncthreads();
    int node = tid >> 3, sub = tid & 7;
    int g = (b << RSHIFT) + node;
    int o0 = off_s[node], o1 = off_s[node + 1];
    float s = 0.f;
    for (int k = o0 + sub; k < o1; k += 8) {
        unsigned p = binned[s0 + k];
        s += wbv[p & 0x1FFFF];
    }
    s += __shfl_xor(s, 1, 8);
    s += __shfl_xor(s, 2, 8);
    s += __shfl_xor(s, 4, 8);
    if (sub == 0) {
        float tval = 0.f; int gid = -1;
        if (g < n) {
            float di = dinv[g];
            tval = sc[1] + di * s + di * di * v[g];
            gid = batch[g];
        }
        tbuf[node] = tval;
        gbuf[node] = gid;
    }
    __syncthreads();
    if (tid < RNODES) {
        int g2 = (b << RSHIFT) + tid;
        if (g2 < n) {
            int gid = gbuf[tid];
            bool head = (tid == 0) || (gbuf[tid - 1] != gid);
            if (head) {
                float sum = 0.f;
                int i2 = tid;
                while (i2 < RNODES && gbuf[i2] == gid) { sum += tbuf[i2]; ++i2; }
                atomicAdd(&out[gid], sum);
            }
        }
    }
}

extern "C" void kernel_launch(void* const* d_in, const int* in_sizes, int n_in,
                              void* d_out, int out_size, void* d_ws, size_t ws_size,
                              hipStream_t stream)
{
    const float* x    = (const float*)d_in[0];
    const int*   ei   = (const int*)d_in[1];
    const int*   batch= (const int*)d_in[2];
    const float* W1   = (const float*)d_in[3];
    const float* b1   = (const float*)d_in[4];
    const float* W2   = (const float*)d_in[5];
    const float* b2   = (const float*)d_in[6];
    const float* Wf1  = (const float*)d_in[7];
    const float* bf1  = (const float*)d_in[8];
    const float* Wf2  = (const float*)d_in[9];
    const float* bf2  = (const float*)d_in[10];
    const float* Wf3  = (const float*)d_in[11];
    const float* bf3  = (const float*)d_in[12];
    const float* Wo   = (const float*)d_in[13];
    const float* bo   = (const float*)d_in[14];
    float* out = (float*)d_out;

    const int n = in_sizes[0] / 64;
    const int E = in_sizes[1] / 2;
    const int G = out_size;
    const int* src = ei;
    const int* dst = ei + E;
    const int nb = (n + RNODES - 1) >> RSHIFT;

    // workspace layout (element offsets, all blocks 16B-aligned)
    float* ws_f = (float*)d_ws;
    int*   ws_i = (int*)d_ws;
    int*   cursor = ws_i;                    // NB_MAX  (zeroed by memset below)
    float* scG    = ws_f + NB_MAX;           // 3 (+pad to 16)
    size_t off_u  = NB_MAX + 16;
    float* u      = ws_f + off_u;            // n
    float* dinv   = u + n;                   // n
    float* w      = dinv + n;                // n
    float* v      = w + n;                   // n
    float* wb     = v + n;                   // n
    int*   offG   = ws_i + off_u + 5*(size_t)n;   // n
    size_t off_b  = off_u + 6*(size_t)n;
    off_b = (off_b + 3) & ~(size_t)3;
    unsigned int* binned = (unsigned int*)(ws_f + off_b);   // nb * BCAP

    const int NT = (E + STAGE_CAP - 1) / STAGE_CAP;   // scatter tiles
    const int npb = (n + NT - 1) / NT;                // nodes per tile for u

    hipMemsetAsync(cursor, 0, NB_MAX * sizeof(int), stream);
    hipLaunchKernelGGL(scatter_k, dim3(NT), dim3(STHREADS), 0, stream,
                       x, src, dst,
                       W1, b1, W2, b2, Wf1, bf1, Wf2, bf2, Wf3, bf3, Wo, bo,
                       u, scG, E, n, npb, nb, cursor, binned);
    hipLaunchKernelGGL(sort_dinv_k, dim3(nb), dim3(CTHREADS), 0, stream,
                       binned, cursor, u, dinv, w, offG, n);
    hipLaunchKernelGGL(conv_mid_k, dim3(nb), dim3(CTHREADS), 0, stream,
                       binned, cursor, offG, w, dinv, u, scG, v, wb, out, n, G);
    hipLaunchKernelGGL(conv_final_k, dim3(nb), dim3(CTHREADS), 0, stream,
                       binned, cursor, offG, wb, dinv, v, scG, batch, out, n);
}